// Round 7
// baseline (67.856 us; speedup 1.0000x reference)
//
#include <hip/hip_runtime.h>
#include <hip/hip_bf16.h>

#define DDIM 4096
#define NROWS 16384
#define SK_ITERS 20
#define KC 256      // K-floats per chunk (per row)
#define NCH 16      // DDIM / KC

typedef __attribute__((ext_vector_type(8))) __bf16 bf16x8;
typedef __attribute__((ext_vector_type(4))) float f32x4;
typedef __attribute__((ext_vector_type(4))) int   i32x4;

// Cooperative-staging variant keeping ALL proven pipeline invariants:
//  - issue-at-top, depth-3, counted per-wave vmcnt, raw s_barrier (no drain)
//  - block = 4 waves x 16 rows; wave w DMA-stages rows {4w..4w+3} over the
//    FULL chunk width: each global_load_lds = 1 KB CONTIGUOUS from one row
//    -> 16 sequential streams/block @1KB bursts (vs r6's 64 streams @128B)
//  - waves split K within the chunk (wave w computes k-subrange w*64..+64);
//    k-partials combined in the epilogue
//  - 4-buffer ring x 16 KB = 64 KB LDS -> 2 blocks/CU = 8 waves/CU
//  - XOR swizzle: LDS[row][g] = x_row[g ^ (row&7)] via lane-permuted source
//    (linear DMA dest), undone on ds_read -> 2-way bank alias only (free)
// Buffer-reuse safety: issue(c+3) at iter-c top overwrites buf[(c-1)&3];
// all waves finished reading it at the iter-(c-1) end-of-compute barrier.
// k-bijection (A and B identical): k = c*256 + wave*64 + st*32 + kq*8 + i.
__global__ __launch_bounds__(256, 2)
void rsm_kernel(const float* __restrict__ x, const float* __restrict__ W,
                const float* __restrict__ bias, const float* __restrict__ alpha_p,
                float* __restrict__ out)
{
    __shared__ __align__(16) float lds[4][16][KC];   // 64 KB

    const int tid  = threadIdx.x;
    const int wave = tid >> 6;
    const int lane = tid & 63;
    const int r16  = lane & 15;   // A row-in-tile, W row (output col), C col
    const int kq   = lane >> 4;
    const int z    = r16 & 7;
    const int rowbase = blockIdx.x * 16;

    // DMA sources: wave stages rows wave*4 + jj; one 1KB window per instr,
    // lanes permuted by ^ (row&7) at 16B granularity within the window.
    const float* sbase[4];
#pragma unroll
    for (int jj = 0; jj < 4; ++jj) {
        int row = wave * 4 + jj;
        sbase[jj] = x + (size_t)(rowbase + row) * DDIM + ((lane ^ (row & 7)) << 2);
    }

    const float* wq = W + (size_t)r16 * DDIM + wave * 64 + kq * 8;

    i32x4 wr[4][4];   // W fp32 ring (static idx after full unroll)

    // group g_c = [4 W dwordx4][4 DMA 1KB] = 8 vm ops per wave
    auto issue = [&](int c) {
        const float* p = wq + c * KC;
        i32x4* wd = wr[c & 3];
        asm volatile(
            "global_load_dwordx4 %0, %4, off\n\t"
            "global_load_dwordx4 %1, %4, off offset:16\n\t"
            "global_load_dwordx4 %2, %4, off offset:128\n\t"
            "global_load_dwordx4 %3, %4, off offset:144"
            : "=&v"(wd[0]), "=&v"(wd[1]), "=&v"(wd[2]), "=&v"(wd[3])
            : "v"(p));
#pragma unroll
        for (int jj = 0; jj < 4; ++jj) {
            __builtin_amdgcn_global_load_lds(
                (const __attribute__((address_space(1))) void*)(sbase[jj] + c * KC),
                (__attribute__((address_space(3))) void*)(&lds[c & 3][wave * 4 + jj][0]),
                16, 0, 0);
        }
    };

    issue(0);
    issue(1);
    issue(2);

    f32x4 acc = {0.f, 0.f, 0.f, 0.f};
    float sumsq = 0.f;

#pragma unroll
    for (int c = 0; c < NCH; ++c) {
        if (c + 3 < NCH) issue(c + 3);
        __builtin_amdgcn_sched_barrier(0);
        if (c + 3 < NCH)       asm volatile("s_waitcnt vmcnt(24)" ::: "memory");
        else if (c == NCH - 3) asm volatile("s_waitcnt vmcnt(16)" ::: "memory");
        else if (c == NCH - 2) asm volatile("s_waitcnt vmcnt(8)"  ::: "memory");
        else                   asm volatile("s_waitcnt vmcnt(0)"  ::: "memory");
        __builtin_amdgcn_sched_barrier(0);
        asm volatile("s_barrier" ::: "memory");   // all 4 waves' chunk-c landed
        __builtin_amdgcn_sched_barrier(0);

        const float* arow = &lds[c & 3][r16][0];
#pragma unroll
        for (int st = 0; st < 2; ++st) {
            const int g0 = wave * 16 + st * 8 + kq * 2;
            f32x4 a0 = *(const f32x4*)(arow + (((g0    ) ^ z) << 2));
            f32x4 a1 = *(const f32x4*)(arow + (((g0 + 1) ^ z) << 2));

            sumsq += a0[0]*a0[0] + a0[1]*a0[1] + a0[2]*a0[2] + a0[3]*a0[3]
                   + a1[0]*a1[0] + a1[1]*a1[1] + a1[2]*a1[2] + a1[3]*a1[3];

            f32x4 b0 = __builtin_bit_cast(f32x4, wr[c & 3][st * 2]);
            f32x4 b1 = __builtin_bit_cast(f32x4, wr[c & 3][st * 2 + 1]);

            bf16x8 af, bv;
            af[0]=(__bf16)a0[0]; af[1]=(__bf16)a0[1]; af[2]=(__bf16)a0[2]; af[3]=(__bf16)a0[3];
            af[4]=(__bf16)a1[0]; af[5]=(__bf16)a1[1]; af[6]=(__bf16)a1[2]; af[7]=(__bf16)a1[3];
            bv[0]=(__bf16)b0[0]; bv[1]=(__bf16)b0[1]; bv[2]=(__bf16)b0[2]; bv[3]=(__bf16)b0[3];
            bv[4]=(__bf16)b1[0]; bv[5]=(__bf16)b1[1]; bv[6]=(__bf16)b1[2]; bv[7]=(__bf16)b1[3];

            acc = __builtin_amdgcn_mfma_f32_16x16x32_bf16(af, bv, acc, 0, 0, 0);
        }

        __builtin_amdgcn_sched_barrier(0);
        asm volatile("s_barrier" ::: "memory");   // all waves done reading buf
    }

    // ---- epilogue: combine K-partials across waves, RMS scale, Sinkhorn ----
    __syncthreads();   // one-time full drain; LDS now reusable
    float* sc = &lds[0][0][0];
    *(f32x4*)(sc + wave * 256 + lane * 4) = acc;
    sc[1024 + wave * 64 + lane] = sumsq;
    __syncthreads();

    if (wave == 0) {
        f32x4 cg = *(const f32x4*)(sc + lane * 4);
#pragma unroll
        for (int w = 1; w < 4; ++w)
            cg += *(const f32x4*)(sc + w * 256 + lane * 4);

        float s = sc[1024 + lane] + sc[1024 + 64 + lane]
                + sc[1024 + 128 + lane] + sc[1024 + 192 + lane];
        s += __shfl_xor(s, 16);
        s += __shfl_xor(s, 32);          // s = S[r16] in every lane

        const float al = alpha_p[0];
        const float bi = bias[r16];

        float m[4];
#pragma unroll
        for (int r = 0; r < 4; ++r) {
            float Srow  = __shfl(s, kq * 4 + r);   // token row of cg[r]
            float scale = rsqrtf(Srow * (1.0f / DDIM) + 1.1920929e-07f);  // fp32 eps
            m[r] = expf(al * (cg[r] * scale) + bi);
        }

        for (int it = 0; it < SK_ITERS; ++it) {
#pragma unroll
            for (int r = 0; r < 4; ++r) {          // col normalize: sum over i (bits 2,3)
                float t = m[r] + __shfl_xor(m[r], 4);
                t += __shfl_xor(t, 8);
                m[r] = m[r] / (t + 1e-8f);
            }
#pragma unroll
            for (int r = 0; r < 4; ++r) {          // row normalize: sum over j (bits 0,1)
                float t = m[r] + __shfl_xor(m[r], 1);
                t += __shfl_xor(t, 2);
                m[r] = m[r] / (t + 1e-8f);
            }
        }

#pragma unroll
        for (int r = 0; r < 4; ++r)
            out[(size_t)(rowbase + kq * 4 + r) * 16 + r16] = m[r];
    }
}

extern "C" void kernel_launch(void* const* d_in, const int* in_sizes, int n_in,
                              void* d_out, int out_size, void* d_ws, size_t ws_size,
                              hipStream_t stream) {
    const float* x     = (const float*)d_in[0];
    const float* W     = (const float*)d_in[1];
    const float* bias  = (const float*)d_in[2];
    const float* alpha = (const float*)d_in[3];
    float* out = (float*)d_out;

    rsm_kernel<<<dim3(NROWS / 16), dim3(256), 0, stream>>>(x, W, bias, alpha, out);
}

// Round 8
// 48.454 us; speedup vs baseline: 1.4004x; 1.4004x over previous
//
#include <hip/hip_runtime.h>
#include <hip/hip_bf16.h>

#define DDIM 4096
#define NROWS 16384
#define SK_ITERS 20
#define KC 32       // K-floats per chunk per wave
#define NCH 32      // 1024 / KC chunks per wave (K-quarter)

typedef __attribute__((ext_vector_type(8))) __bf16 bf16x8;
typedef __attribute__((ext_vector_type(4))) float f32x4;
typedef __attribute__((ext_vector_type(4))) int   i32x4;

// r6's proven main loop (barrier-free, wave-private 4-buf ring, depth-3,
// issue-at-top, counted per-wave vmcnt, 16 waves/CU), with the epilogue
// parallelized across all 256 threads: thread t owns token tr=t>>4, matrix
// entry c16=t&15 (one output element each). Sinkhorn uses rcp*mul and fast
// exp; the output store is fully coalesced (thread t -> out[rowbase*16+t]).
// k-bijection (A and B identical): k = wave*1024 + c*32 + kq*8 + i.
__global__ __launch_bounds__(256, 4)
void rsm_kernel(const float* __restrict__ x, const float* __restrict__ W,
                const float* __restrict__ bias, const float* __restrict__ alpha_p,
                float* __restrict__ out)
{
    __shared__ __align__(16) float lds[4][4][16][KC];   // [wave][buf][row][k] = 32 KB

    const int tid  = threadIdx.x;
    const int wave = tid >> 6;
    const int lane = tid & 63;
    const int r16  = lane & 15;   // A row-in-tile, W row (output col), C col
    const int kq   = lane >> 4;
    const int z    = r16 & 7;
    const int rowbase = blockIdx.x * 16;

    // DMA instr j stages rows j*8 + (lane>>3); lane writes LDS linearly at
    // (row, phys granule lane&7) <- global granule (lane&7) ^ (lane>>3).
    const float* sbase[2];
#pragma unroll
    for (int j = 0; j < 2; ++j) {
        int row = j * 8 + (lane >> 3);
        sbase[j] = x + (size_t)(rowbase + row) * DDIM + wave * 1024
                 + (((lane & 7) ^ (lane >> 3)) << 2);
    }

    const float* wq = W + (size_t)r16 * DDIM + wave * 1024 + kq * 8;

    i32x4 wr[4][2];   // W fp32 ring (static idx c&3 after full unroll)

    // group g_c = [2 W dwordx4][2 DMA] = 4 vm ops
    auto issue = [&](int c) {
        const float* p = wq + c * KC;
        asm volatile(
            "global_load_dwordx4 %0, %2, off\n\t"
            "global_load_dwordx4 %1, %2, off offset:16"
            : "=&v"(wr[c & 3][0]), "=&v"(wr[c & 3][1])
            : "v"(p));
#pragma unroll
        for (int j = 0; j < 2; ++j) {
            __builtin_amdgcn_global_load_lds(
                (const __attribute__((address_space(1))) void*)(sbase[j] + c * KC),
                (__attribute__((address_space(3))) void*)(&lds[wave][c & 3][j * 8][0]),
                16, 0, 0);
        }
    };

    issue(0);
    issue(1);
    issue(2);

    f32x4 acc = {0.f, 0.f, 0.f, 0.f};
    float sumsq = 0.f;

#pragma unroll
    for (int c = 0; c < NCH; ++c) {
        if (c + 3 < NCH) issue(c + 3);
        __builtin_amdgcn_sched_barrier(0);
        if (c + 3 < NCH)       asm volatile("s_waitcnt vmcnt(12)" ::: "memory");
        else if (c == NCH - 3) asm volatile("s_waitcnt vmcnt(8)" ::: "memory");
        else if (c == NCH - 2) asm volatile("s_waitcnt vmcnt(4)" ::: "memory");
        else                   asm volatile("s_waitcnt vmcnt(0)" ::: "memory");
        __builtin_amdgcn_sched_barrier(0);

        const float* arow = &lds[wave][c & 3][r16][0];
        f32x4 a0 = *(const f32x4*)(arow + (((kq * 2    ) ^ z) << 2));
        f32x4 a1 = *(const f32x4*)(arow + (((kq * 2 + 1) ^ z) << 2));

        sumsq += a0[0]*a0[0] + a0[1]*a0[1] + a0[2]*a0[2] + a0[3]*a0[3]
               + a1[0]*a1[0] + a1[1]*a1[1] + a1[2]*a1[2] + a1[3]*a1[3];

        f32x4 b0 = __builtin_bit_cast(f32x4, wr[c & 3][0]);
        f32x4 b1 = __builtin_bit_cast(f32x4, wr[c & 3][1]);

        bf16x8 af, bv;
        af[0]=(__bf16)a0[0]; af[1]=(__bf16)a0[1]; af[2]=(__bf16)a0[2]; af[3]=(__bf16)a0[3];
        af[4]=(__bf16)a1[0]; af[5]=(__bf16)a1[1]; af[6]=(__bf16)a1[2]; af[7]=(__bf16)a1[3];
        bv[0]=(__bf16)b0[0]; bv[1]=(__bf16)b0[1]; bv[2]=(__bf16)b0[2]; bv[3]=(__bf16)b0[3];
        bv[4]=(__bf16)b1[0]; bv[5]=(__bf16)b1[1]; bv[6]=(__bf16)b1[2]; bv[7]=(__bf16)b1[3];

        acc = __builtin_amdgcn_mfma_f32_16x16x32_bf16(af, bv, acc, 0, 0, 0);
    }

    // ---- epilogue: all-thread combine + RMS + Sinkhorn (1 element/thread) ----
    __syncthreads();   // one-time full drain; LDS now reusable
    float* sc = &lds[0][0][0][0];
    // C partials: addr(w, token, col) = w*256 + (token>>2)*64 + col*4 + (token&3)
    //   (acc[r] at lane holds C[token = kq*4+r][col = r16] for K-quarter `wave`)
    *(f32x4*)(sc + wave * 256 + lane * 4) = acc;
    // sumsq: fold kq-groups now so each lane holds the full row-partial for r16
    float sq = sumsq;
    sq += __shfl_xor(sq, 16);
    sq += __shfl_xor(sq, 32);
    if (lane < 16) sc[1024 + wave * 16 + lane] = sq;   // [w][row]
    __syncthreads();

    const int tr  = tid >> 4;    // token row in tile
    const int c16 = tid & 15;    // output entry n = n1*4 + n2
    const int ca  = (tr >> 2) * 64 + c16 * 4 + (tr & 3);

    float cg = sc[ca] + sc[256 + ca] + sc[512 + ca] + sc[768 + ca];
    float S  = sc[1024 + tr] + sc[1024 + 16 + tr]
             + sc[1024 + 32 + tr] + sc[1024 + 48 + tr];

    float scale = rsqrtf(S * (1.0f / DDIM) + 1.1920929e-07f);  // fp32 eps
    float h = alpha_p[0] * (cg * scale) + bias[c16];
    float m = __expf(h);

    // Sinkhorn: col-normalize sums over n1 (bits 3,2 of c16 -> xor 4,8);
    // row-normalize sums over n2 (bits 1,0 -> xor 1,2). rcp+mul (approx ~1e-6).
    for (int it = 0; it < SK_ITERS; ++it) {
        float t1 = m + __shfl_xor(m, 4);
        t1 += __shfl_xor(t1, 8);
        m = m * __builtin_amdgcn_rcpf(t1 + 1e-8f);
        float t2 = m + __shfl_xor(m, 1);
        t2 += __shfl_xor(t2, 2);
        m = m * __builtin_amdgcn_rcpf(t2 + 1e-8f);
    }

    out[(size_t)rowbase * 16 + tid] = m;   // fully coalesced, 4 KB/block
}

extern "C" void kernel_launch(void* const* d_in, const int* in_sizes, int n_in,
                              void* d_out, int out_size, void* d_ws, size_t ws_size,
                              hipStream_t stream) {
    const float* x     = (const float*)d_in[0];
    const float* W     = (const float*)d_in[1];
    const float* bias  = (const float*)d_in[2];
    const float* alpha = (const float*)d_in[3];
    float* out = (float*)d_out;

    rsm_kernel<<<dim3(NROWS / 16), dim3(256), 0, stream>>>(x, W, bias, alpha, out);
}